// Round 13
// baseline (146.828 us; speedup 1.0000x reference)
//
#include <hip/hip_runtime.h>
#include <hip/hip_bf16.h>
#include <stdint.h>

#define NB 256
#define LQ 128
#define LC 512
#define DIM 384
#define CBP 392     // bf16 tile pitch in shorts (784 B)
#define TR 64       // rows per stage
#define NST 10      // 2 q tiles + 8 c tiles
#define NQS 2

typedef __attribute__((ext_vector_type(8))) short short8;
typedef __attribute__((ext_vector_type(4))) float f4;
typedef __attribute__((ext_vector_type(2))) unsigned int u32x2;

__device__ __forceinline__ unsigned int pk2bf(float a, float b) {
  union { float f; uint32_t u; } x, y; x.f = a; y.f = b;
  uint32_t lo = (x.u + 0x7fffu + ((x.u >> 16) & 1u)) >> 16;
  uint32_t hi = (y.u + 0x7fffu + ((y.u >> 16) & 1u)) >> 16;
  return lo | (hi << 16);
}

// =================== fused single-pass, 64-row stages ========================
// Round-13: identical to round-12 fused5 EXCEPT __launch_bounds__(512,1):
// round-12's VGPR demand (~210) was capped at 128 -> 57 MB of scratch spills
// (WRITE_SIZE counter) which masked the barrier-halving experiment. With the
// cap lifted the banks + A-frags live in registers. Grid 256 = 1 block/CU
// either way, so occupancy is unchanged; only the spills go away.
__global__ __launch_bounds__(512, 1)
void fused5(const float* __restrict__ qtok, const float* __restrict__ ctok,
            const int* __restrict__ qm, const int* __restrict__ cm,
            float* __restrict__ pooled, float* __restrict__ late) {
  __shared__ unsigned short s_cb[2][TR][CBP];  // 100352 B (epilogue: f32 arena)
  __shared__ float s_qi[LQ];
  __shared__ float s_ci[2][TR];
  __shared__ int s_qm[LQ];
  __shared__ int s_cm[LC];
  __shared__ float s_cnt[16];
  __shared__ float s_wsum[8];

  const int b = blockIdx.x, tid = threadIdx.x;
  const int wave = tid >> 6, lane = tid & 63;
  const int rA = lane & 15, hi = lane >> 4;
  const bool hiHalf = lane >= 32;
  const int l31 = lane & 31;

  const float* qb = qtok + (size_t)b * LQ * DIM;
  const float* cb = ctok + (size_t)b * LC * DIM;

  s_cm[tid] = cm[b * LC + tid];
  if (tid < LQ) s_qm[tid] = qm[b * LQ + tid];
  __syncthreads();

  f4 v0[8], h0[4], v1[8], h1[4];
  f4 pqA = {0,0,0,0}, pqB = {0,0,0,0}, pcA = {0,0,0,0}, pcB = {0,0,0,0};
  float cq = 0.f, cc = 0.f;
  float rm[4] = {-1e9f, -1e9f, -1e9f, -1e9f};
  short8 A[12] = {};

#define TBASE(t) (((t) < NQS) ? (qb + (size_t)(t) * TR * DIM) \
                              : (cb + (size_t)((t) - NQS) * TR * DIM))

// wave owns rows [wave*8, wave*8+8). v[i] = row i, f4-chunk `lane` (dims<256);
// h[j] = row 2j+(lane>=32), chunk 64+(lane&31) (dims 256..383).
#define ISSUE(V, H, base_) do {                                              \
    const float* bb_ = (base_);                                              \
    _Pragma("unroll")                                                        \
    for (int i_ = 0; i_ < 8; ++i_)                                           \
      V[i_] = *((const f4*)(bb_ + (size_t)(wave * 8 + i_) * DIM) + lane);    \
    _Pragma("unroll")                                                        \
    for (int j_ = 0; j_ < 4; ++j_)                                           \
      H[j_] = *((const f4*)(bb_ + (size_t)(wave * 8 + 2 * j_ +               \
                (hiHalf ? 1 : 0)) * DIM) + 64 + l31);                        \
  } while (0)

#define STAGE(T, V, H, BUF) do {                                             \
    const int t_ = (T);                                                      \
    if (t_ == NST - 1) { asm volatile("s_waitcnt vmcnt(0)" ::: "memory"); }  \
    else               { asm volatile("s_waitcnt vmcnt(12)" ::: "memory"); } \
    __builtin_amdgcn_sched_barrier(0);                                       \
    const bool isq_ = t_ < NQS;                                              \
    const int* mk_ = isq_ ? (s_qm + t_ * TR) : (s_cm + (t_ - NQS) * TR);     \
    float ss_[8];                                                            \
    _Pragma("unroll")                                                        \
    for (int i_ = 0; i_ < 8; ++i_) {                                         \
      const int lr_ = wave * 8 + i_;                                         \
      u32x2 w_; w_[0] = pk2bf(V[i_].x, V[i_].y); w_[1] = pk2bf(V[i_].z, V[i_].w); \
      *(u32x2*)&s_cb[BUF][lr_][4 * lane] = w_;                               \
      ss_[i_] = V[i_].x * V[i_].x + V[i_].y * V[i_].y                        \
              + V[i_].z * V[i_].z + V[i_].w * V[i_].w;                       \
    }                                                                        \
    _Pragma("unroll")                                                        \
    for (int j_ = 0; j_ < 4; ++j_) {                                         \
      const int lr_ = wave * 8 + 2 * j_ + (hiHalf ? 1 : 0);                  \
      u32x2 w_; w_[0] = pk2bf(H[j_].x, H[j_].y); w_[1] = pk2bf(H[j_].z, H[j_].w); \
      *(u32x2*)&s_cb[BUF][lr_][256 + 4 * l31] = w_;                          \
      const float td_ = H[j_].x * H[j_].x + H[j_].y * H[j_].y               \
                      + H[j_].z * H[j_].z + H[j_].w * H[j_].w;              \
      if (hiHalf) ss_[2 * j_ + 1] += td_; else ss_[2 * j_] += td_;           \
    }                                                                        \
    _Pragma("unroll")                                                        \
    for (int o_ = 32; o_; o_ >>= 1) {                                        \
      _Pragma("unroll")                                                      \
      for (int i_ = 0; i_ < 8; ++i_) ss_[i_] += __shfl_xor(ss_[i_], o_);     \
    }                                                                        \
    float fm_[8];                                                            \
    _Pragma("unroll")                                                        \
    for (int i_ = 0; i_ < 8; ++i_) fm_[i_] = (float)mk_[wave * 8 + i_];      \
    if (isq_) {                                                              \
      _Pragma("unroll")                                                      \
      for (int i_ = 0; i_ < 8; ++i_) { pqA += V[i_] * fm_[i_]; cq += fm_[i_]; } \
      _Pragma("unroll")                                                      \
      for (int j_ = 0; j_ < 4; ++j_)                                         \
        pqB += H[j_] * (hiHalf ? fm_[2 * j_ + 1] : fm_[2 * j_]);             \
      if (lane == 0) {                                                       \
        _Pragma("unroll")                                                    \
        for (int i_ = 0; i_ < 8; ++i_)                                       \
          s_qi[t_ * TR + wave * 8 + i_] = 1.0f / fmaxf(sqrtf(ss_[i_]), 1e-12f); \
      }                                                                      \
    } else {                                                                 \
      _Pragma("unroll")                                                      \
      for (int i_ = 0; i_ < 8; ++i_) { pcA += V[i_] * fm_[i_]; cc += fm_[i_]; } \
      _Pragma("unroll")                                                      \
      for (int j_ = 0; j_ < 4; ++j_)                                         \
        pcB += H[j_] * (hiHalf ? fm_[2 * j_ + 1] : fm_[2 * j_]);             \
      if (lane == 0) {                                                       \
        _Pragma("unroll")                                                    \
        for (int i_ = 0; i_ < 8; ++i_)                                       \
          s_ci[BUF][wave * 8 + i_] = 1.0f / fmaxf(sqrtf(ss_[i_]), 1e-12f);   \
      }                                                                      \
    }                                                                        \
    if (t_ + 2 < NST) { ISSUE(V, H, TBASE(t_ + 2)); }                        \
    asm volatile("s_waitcnt lgkmcnt(0)" ::: "memory");                       \
    __builtin_amdgcn_s_barrier();                                            \
    __builtin_amdgcn_sched_barrier(0);                                       \
    if (isq_) {                                                              \
      if ((wave >> 2) == t_) {  /* waves 4t..4t+3 own q rows [64t, 64t+64) */ \
        const int lb_ = (wave & 3) * 16 + rA;                                \
        _Pragma("unroll")                                                    \
        for (int kk_ = 0; kk_ < 12; ++kk_)                                   \
          A[kk_] = *(const short8*)&s_cb[BUF][lb_][kk_ * 32 + hi * 8];       \
        asm volatile("s_waitcnt lgkmcnt(0)" ::: "memory");                   \
        __builtin_amdgcn_sched_barrier(0);                                   \
      }                                                                      \
    } else {                                                                 \
      f4 a_[4] = {{0,0,0,0},{0,0,0,0},{0,0,0,0},{0,0,0,0}};                  \
      _Pragma("unroll")                                                      \
      for (int kk_ = 0; kk_ < 12; ++kk_) {                                   \
        _Pragma("unroll")                                                    \
        for (int cs_ = 0; cs_ < 4; ++cs_) {                                  \
          const short8 b_ = *(const short8*)&s_cb[BUF][cs_ * 16 + rA][kk_ * 32 + hi * 8]; \
          a_[cs_] = __builtin_amdgcn_mfma_f32_16x16x32_bf16(A[kk_], b_, a_[cs_], 0, 0, 0); \
        }                                                                    \
      }                                                                      \
      const int tb_ = (t_ - NQS) * TR;                                       \
      _Pragma("unroll")                                                      \
      for (int cs_ = 0; cs_ < 4; ++cs_) {                                    \
        const bool m_ = s_cm[tb_ + cs_ * 16 + rA] != 0;                      \
        const float ci_ = s_ci[BUF][cs_ * 16 + rA];                          \
        _Pragma("unroll")                                                    \
        for (int r_ = 0; r_ < 4; ++r_) {                                     \
          const float qi_ = s_qi[wave * 16 + hi * 4 + r_];                   \
          const float x_ = m_ ? a_[cs_][r_] * (qi_ * ci_) : -1e9f;           \
          rm[r_] = fmaxf(rm[r_], x_);                                        \
        }                                                                    \
      }                                                                      \
    }                                                                        \
  } while (0)

  // prologue: banks for tiles 0 and 1 in flight (24 loads outstanding)
  ISSUE(v0, h0, TBASE(0));
  ISSUE(v1, h1, TBASE(1));

  for (int t = 0; t < NST; t += 2) {
    STAGE(t, v0, h0, 0);
    STAGE(t + 1, v1, h1, 1);
  }

  // ---------------- epilogue ----------------
#pragma unroll
  for (int r = 0; r < 4; ++r) {
#pragma unroll
    for (int o = 1; o < 16; o <<= 1) rm[r] = fmaxf(rm[r], __shfl_xor(rm[r], o));
  }
  float ps = 0.f;
  if (rA == 0) {
    const int rowb = wave * 16 + hi * 4;
#pragma unroll
    for (int r = 0; r < 4; ++r) ps += s_qm[rowb + r] ? rm[r] : 0.f;
  }
#pragma unroll
  for (int o = 32; o; o >>= 1) ps += __shfl_xor(ps, o);
  if (lane == 0) s_wsum[wave] = ps;

  __syncthreads();  // last-stage LDS reads done before arena reuse

  float* red = (float*)&s_cb[0][0][0];  // [8 waves][2 (q,c)][512] f32 = 32 KB
  *(f4*)&red[(wave * 2 + 0) * 512 + 4 * lane] = pqA;
  *(f4*)&red[(wave * 2 + 0) * 512 + 256 + (hiHalf ? 128 : 0) + 4 * l31] = pqB;
  *(f4*)&red[(wave * 2 + 1) * 512 + 4 * lane] = pcA;
  *(f4*)&red[(wave * 2 + 1) * 512 + 256 + (hiHalf ? 128 : 0) + 4 * l31] = pcB;
  if (lane == 0) { s_cnt[wave] = cq; s_cnt[8 + wave] = cc; }
  __syncthreads();

  if (tid < DIM) {
    float sq = 0.f, sc = 0.f, nq = 0.f, nc = 0.f;
    if (tid < 256) {
#pragma unroll
      for (int w = 0; w < 8; ++w) {
        sq += red[(w * 2 + 0) * 512 + tid];
        sc += red[(w * 2 + 1) * 512 + tid];
      }
    } else {
#pragma unroll
      for (int w = 0; w < 8; ++w) {
        sq += red[(w * 2 + 0) * 512 + tid] + red[(w * 2 + 0) * 512 + tid + 128];
        sc += red[(w * 2 + 1) * 512 + tid] + red[(w * 2 + 1) * 512 + tid + 128];
      }
    }
#pragma unroll
    for (int w = 0; w < 8; ++w) { nq += s_cnt[w]; nc += s_cnt[8 + w]; }
    pooled[b * DIM + tid] = sq / fmaxf(nq, 1e-9f);
    pooled[(NB + b) * DIM + tid] = sc / fmaxf(nc, 1e-9f);
  }
  if (tid == 0) {
    float tot = 0.f;
#pragma unroll
    for (int w = 0; w < 8; ++w) tot += s_wsum[w];
    late[b] = tot;
  }
}

// ================= tail kernels: round-1/9 proven shapes =====================
__global__ __launch_bounds__(DIM)
void mlp_v1(const float* __restrict__ pooled,
            const float* __restrict__ W1, const float* __restrict__ b1,
            const float* __restrict__ W2, const float* __restrict__ b2,
            float* __restrict__ emb) {
  __shared__ float s_in[DIM];
  __shared__ float s_h[DIM];
  __shared__ float s_red[6];
  const int row = blockIdx.y * NB + blockIdx.x;
  const int d = threadIdx.x;
  s_in[d] = pooled[(size_t)row * DIM + d];
  __syncthreads();
  float acc = b1[d];
#pragma unroll 8
  for (int k = 0; k < DIM; ++k) acc = fmaf(s_in[k], W1[k * DIM + d], acc);
  s_h[d] = fmaxf(acc, 0.f);
  __syncthreads();
  float p = b2[d];
#pragma unroll 8
  for (int k = 0; k < DIM; ++k) p = fmaf(s_h[k], W2[k * DIM + d], p);
  float ss = p * p;
#pragma unroll
  for (int o = 32; o; o >>= 1) ss += __shfl_xor(ss, o);
  if ((d & 63) == 0) s_red[d >> 6] = ss;
  __syncthreads();
  float tot = 0.f;
#pragma unroll
  for (int w = 0; w < 6; ++w) tot += s_red[w];
  emb[(size_t)row * DIM + d] = p * (1.0f / fmaxf(sqrtf(tot), 1e-12f));
}

__global__ __launch_bounds__(NB)
void contrast_kernel(const float* __restrict__ emb, float* __restrict__ out0) {
  __shared__ float s_q[DIM];
  const int i = blockIdx.x;
  for (int k = threadIdx.x; k < DIM; k += NB) s_q[k] = emb[(size_t)i * DIM + k];
  __syncthreads();
  const float* ce = emb + (size_t)(NB + threadIdx.x) * DIM;
  float acc = 0.f;
#pragma unroll 8
  for (int k = 0; k < DIM; ++k) acc = fmaf(s_q[k], ce[k], acc);
  out0[(size_t)i * NB + threadIdx.x] = acc / 0.07f;
}

// ============================== launch =======================================
extern "C" void kernel_launch(void* const* d_in, const int* in_sizes, int n_in,
                              void* d_out, int out_size, void* d_ws, size_t ws_size,
                              hipStream_t stream) {
  const float* qtok = (const float*)d_in[0];
  const float* ctok = (const float*)d_in[1];
  const int*   qmm  = (const int*)d_in[2];
  const int*   cmm  = (const int*)d_in[3];
  const float* W1   = (const float*)d_in[4];
  const float* b1   = (const float*)d_in[5];
  const float* W2   = (const float*)d_in[6];
  const float* b2   = (const float*)d_in[7];

  float* out0 = (float*)d_out;            // [NB*NB]
  float* late = out0 + NB * NB;           // [NB]
  float* pooled = (float*)d_ws;           // [2*NB][DIM]
  float* emb    = pooled + 2 * NB * DIM;  // [2*NB][DIM]

  hipLaunchKernelGGL(fused5, dim3(NB), dim3(512), 0, stream,
                     qtok, ctok, qmm, cmm, pooled, late);
  hipLaunchKernelGGL(mlp_v1, dim3(NB, 2), dim3(DIM), 0, stream,
                     pooled, W1, b1, W2, b2, emb);
  hipLaunchKernelGGL(contrast_kernel, dim3(NB), dim3(NB), 0, stream, emb, out0);
}

// Round 14
// 113.144 us; speedup vs baseline: 1.2977x; 1.2977x over previous
//
#include <hip/hip_runtime.h>
#include <hip/hip_bf16.h>
#include <stdint.h>

#define NB 256
#define LQ 128
#define LC 512
#define DIM 384
#define CBP 392     // bf16 tile pitch in shorts (784 B)
#define NST 20      // 4 q tiles + 16 c tiles, 32 rows each
#define NQS 4

typedef __attribute__((ext_vector_type(8))) short short8;
typedef __attribute__((ext_vector_type(4))) float f4;
typedef __attribute__((ext_vector_type(2))) unsigned int u32x2;

__device__ __forceinline__ unsigned int pk2bf(float a, float b) {
  union { float f; uint32_t u; } x, y; x.f = a; y.f = b;
  uint32_t lo = (x.u + 0x7fffu + ((x.u >> 16) & 1u)) >> 16;
  uint32_t hi = (y.u + 0x7fffu + ((y.u >> 16) & 1u)) >> 16;
  return lo | (hi << 16);
}

// ================= fused single-pass, 3-deep register pipeline ===============
// Round-14: r9 structure with (a) q bf16 tile persistent in LDS (A-frags read
// per c-stage, not held in 48 VGPRs) and (b) the freed registers funding a
// THIRD prefetch bank: loads issue 3 stages ahead, vmcnt(12) at stage top,
// 18 f4/lane outstanding continuously. Live-reg estimate ~120 <= the 128 cap
// this toolchain enforces for 512-thread blocks (r12/r13 evidence) -> no
// spills. LDS 154 KB (1 block/CU, which grid=256 forces anyway).
__global__ __launch_bounds__(512, 2)
void fused6(const float* __restrict__ qtok, const float* __restrict__ ctok,
            const int* __restrict__ qm, const int* __restrict__ cm,
            float* __restrict__ pooled, float* __restrict__ late) {
  __shared__ unsigned short s_q[LQ][CBP];      // 100352 B (epilogue: f32 arena)
  __shared__ unsigned short s_c[2][32][CBP];   // 50176 B
  __shared__ float s_qi[LQ];
  __shared__ float s_ci[2][32];
  __shared__ int s_qm[LQ];
  __shared__ int s_cm[LC];
  __shared__ float s_cnt[16];
  __shared__ float s_wsum[8];

  const int b = blockIdx.x, tid = threadIdx.x;
  const int wave = tid >> 6, lane = tid & 63;
  const int rA = lane & 15, hi = lane >> 4;
  const bool hiHalf = lane >= 32;
  const int l31 = lane & 31;

  const float* qb = qtok + (size_t)b * LQ * DIM;
  const float* cb = ctok + (size_t)b * LC * DIM;

  s_cm[tid] = cm[b * LC + tid];
  if (tid < LQ) s_qm[tid] = qm[b * LQ + tid];
  __syncthreads();

  f4 v0[4], h0[2], v1[4], h1[2], v2[4], h2[2];
  f4 pqA = {0,0,0,0}, pqB = {0,0,0,0}, pcA = {0,0,0,0}, pcB = {0,0,0,0};
  float cq = 0.f, cc = 0.f;
  float rm[4] = {-1e9f, -1e9f, -1e9f, -1e9f};

#define TBASE(t) (((t) < NQS) ? (qb + (size_t)(t) * 32 * DIM) \
                              : (cb + (size_t)((t) - NQS) * 32 * DIM))

#define ISSUE(V, H, base_) do {                                              \
    const float* bb_ = (base_);                                              \
    _Pragma("unroll")                                                        \
    for (int i_ = 0; i_ < 4; ++i_)                                           \
      V[i_] = *((const f4*)(bb_ + (size_t)(wave * 4 + i_) * DIM) + lane);    \
    _Pragma("unroll")                                                        \
    for (int j_ = 0; j_ < 2; ++j_)                                           \
      H[j_] = *((const f4*)(bb_ + (size_t)(wave * 4 + 2 * j_ +               \
                (hiHalf ? 1 : 0)) * DIM) + 64 + l31);                        \
  } while (0)

#define STAGE(T, V, H) do {                                                  \
    const int t_ = (T);                                                      \
    if      (t_ == NST - 1) { asm volatile("s_waitcnt vmcnt(0)" ::: "memory"); } \
    else if (t_ == NST - 2) { asm volatile("s_waitcnt vmcnt(6)" ::: "memory"); } \
    else                    { asm volatile("s_waitcnt vmcnt(12)" ::: "memory"); } \
    __builtin_amdgcn_sched_barrier(0);                                       \
    const bool isq_ = t_ < NQS;                                              \
    const int cbuf_ = (t_ - NQS) & 1;                                        \
    const int* mk_ = isq_ ? (s_qm + t_ * 32) : (s_cm + (t_ - NQS) * 32);     \
    unsigned short* dst_ = isq_ ? &s_q[t_ * 32][0] : &s_c[cbuf_][0][0];      \
    float ss_[4];                                                            \
    _Pragma("unroll")                                                        \
    for (int i_ = 0; i_ < 4; ++i_) {                                         \
      const int lr_ = wave * 4 + i_;                                         \
      u32x2 w_; w_[0] = pk2bf(V[i_].x, V[i_].y); w_[1] = pk2bf(V[i_].z, V[i_].w); \
      *(u32x2*)(dst_ + (size_t)lr_ * CBP + 4 * lane) = w_;                   \
      ss_[i_] = V[i_].x * V[i_].x + V[i_].y * V[i_].y                        \
              + V[i_].z * V[i_].z + V[i_].w * V[i_].w;                       \
    }                                                                        \
    _Pragma("unroll")                                                        \
    for (int j_ = 0; j_ < 2; ++j_) {                                         \
      const int lr_ = wave * 4 + 2 * j_ + (hiHalf ? 1 : 0);                  \
      u32x2 w_; w_[0] = pk2bf(H[j_].x, H[j_].y); w_[1] = pk2bf(H[j_].z, H[j_].w); \
      *(u32x2*)(dst_ + (size_t)lr_ * CBP + 256 + 4 * l31) = w_;              \
      const float td_ = H[j_].x * H[j_].x + H[j_].y * H[j_].y               \
                      + H[j_].z * H[j_].z + H[j_].w * H[j_].w;              \
      if (hiHalf) ss_[2 * j_ + 1] += td_; else ss_[2 * j_] += td_;           \
    }                                                                        \
    _Pragma("unroll")                                                        \
    for (int o_ = 32; o_; o_ >>= 1) {                                        \
      _Pragma("unroll")                                                      \
      for (int i_ = 0; i_ < 4; ++i_) ss_[i_] += __shfl_xor(ss_[i_], o_);     \
    }                                                                        \
    float fm_[4];                                                            \
    _Pragma("unroll")                                                        \
    for (int i_ = 0; i_ < 4; ++i_) fm_[i_] = (float)mk_[wave * 4 + i_];      \
    if (isq_) {                                                              \
      _Pragma("unroll")                                                      \
      for (int i_ = 0; i_ < 4; ++i_) { pqA += V[i_] * fm_[i_]; cq += fm_[i_]; } \
      _Pragma("unroll")                                                      \
      for (int j_ = 0; j_ < 2; ++j_)                                         \
        pqB += H[j_] * (hiHalf ? fm_[2 * j_ + 1] : fm_[2 * j_]);             \
      if (lane == 0) {                                                       \
        _Pragma("unroll")                                                    \
        for (int i_ = 0; i_ < 4; ++i_)                                       \
          s_qi[t_ * 32 + wave * 4 + i_] = 1.0f / fmaxf(sqrtf(ss_[i_]), 1e-12f); \
      }                                                                      \
    } else {                                                                 \
      _Pragma("unroll")                                                      \
      for (int i_ = 0; i_ < 4; ++i_) { pcA += V[i_] * fm_[i_]; cc += fm_[i_]; } \
      _Pragma("unroll")                                                      \
      for (int j_ = 0; j_ < 2; ++j_)                                         \
        pcB += H[j_] * (hiHalf ? fm_[2 * j_ + 1] : fm_[2 * j_]);             \
      if (lane == 0) {                                                       \
        _Pragma("unroll")                                                    \
        for (int i_ = 0; i_ < 4; ++i_)                                       \
          s_ci[cbuf_][wave * 4 + i_] = 1.0f / fmaxf(sqrtf(ss_[i_]), 1e-12f); \
      }                                                                      \
    }                                                                        \
    if (t_ + 3 < NST) { ISSUE(V, H, TBASE(t_ + 3)); }                        \
    asm volatile("s_waitcnt lgkmcnt(0)" ::: "memory");                       \
    __builtin_amdgcn_s_barrier();                                            \
    __builtin_amdgcn_sched_barrier(0);                                       \
    if (!isq_) {                                                             \
      f4 a0_ = {0,0,0,0}, a1_ = {0,0,0,0};                                   \
      _Pragma("unroll")                                                      \
      for (int kk_ = 0; kk_ < 12; ++kk_) {                                   \
        const short8 af_ = *(const short8*)&s_q[wave * 16 + rA][kk_ * 32 + hi * 8]; \
        const short8 b0_ = *(const short8*)&s_c[cbuf_][rA][kk_ * 32 + hi * 8];      \
        const short8 b1_ = *(const short8*)&s_c[cbuf_][rA + 16][kk_ * 32 + hi * 8]; \
        a0_ = __builtin_amdgcn_mfma_f32_16x16x32_bf16(af_, b0_, a0_, 0, 0, 0);      \
        a1_ = __builtin_amdgcn_mfma_f32_16x16x32_bf16(af_, b1_, a1_, 0, 0, 0);      \
      }                                                                      \
      const int tb_ = (t_ - NQS) * 32;                                       \
      const bool m0_ = s_cm[tb_ + rA] != 0;                                  \
      const bool m1_ = s_cm[tb_ + rA + 16] != 0;                             \
      const float ci0_ = s_ci[cbuf_][rA], ci1_ = s_ci[cbuf_][rA + 16];       \
      _Pragma("unroll")                                                      \
      for (int r_ = 0; r_ < 4; ++r_) {                                       \
        const float qi_ = s_qi[wave * 16 + hi * 4 + r_];                     \
        const float x0_ = m0_ ? a0_[r_] * (qi_ * ci0_) : -1e9f;              \
        const float x1_ = m1_ ? a1_[r_] * (qi_ * ci1_) : -1e9f;              \
        rm[r_] = fmaxf(rm[r_], fmaxf(x0_, x1_));                             \
      }                                                                      \
    }                                                                        \
  } while (0)

  // prologue: 3 banks in flight (18 loads/lane)
  ISSUE(v0, h0, TBASE(0));
  ISSUE(v1, h1, TBASE(1));
  ISSUE(v2, h2, TBASE(2));

  for (int t = 0; t < 18; t += 3) {
    STAGE(t, v0, h0);
    STAGE(t + 1, v1, h1);
    STAGE(t + 2, v2, h2);
  }
  STAGE(18, v0, h0);
  STAGE(19, v1, h1);

  // ---------------- epilogue ----------------
#pragma unroll
  for (int r = 0; r < 4; ++r) {
#pragma unroll
    for (int o = 1; o < 16; o <<= 1) rm[r] = fmaxf(rm[r], __shfl_xor(rm[r], o));
  }
  float ps = 0.f;
  if (rA == 0) {
    const int rowb = wave * 16 + hi * 4;
#pragma unroll
    for (int r = 0; r < 4; ++r) ps += s_qm[rowb + r] ? rm[r] : 0.f;
  }
#pragma unroll
  for (int o = 32; o; o >>= 1) ps += __shfl_xor(ps, o);
  if (lane == 0) s_wsum[wave] = ps;

  __syncthreads();  // last-stage LDS reads (incl. s_q A-frags) done before reuse

  float* red = (float*)&s_q[0][0];  // [8 waves][2 (q,c)][512] f32 = 32 KB
  *(f4*)&red[(wave * 2 + 0) * 512 + 4 * lane] = pqA;
  *(f4*)&red[(wave * 2 + 0) * 512 + 256 + (hiHalf ? 128 : 0) + 4 * l31] = pqB;
  *(f4*)&red[(wave * 2 + 1) * 512 + 4 * lane] = pcA;
  *(f4*)&red[(wave * 2 + 1) * 512 + 256 + (hiHalf ? 128 : 0) + 4 * l31] = pcB;
  if (lane == 0) { s_cnt[wave] = cq; s_cnt[8 + wave] = cc; }
  __syncthreads();

  if (tid < DIM) {
    float sq = 0.f, sc = 0.f, nq = 0.f, nc = 0.f;
    if (tid < 256) {
#pragma unroll
      for (int w = 0; w < 8; ++w) {
        sq += red[(w * 2 + 0) * 512 + tid];
        sc += red[(w * 2 + 1) * 512 + tid];
      }
    } else {
#pragma unroll
      for (int w = 0; w < 8; ++w) {
        sq += red[(w * 2 + 0) * 512 + tid] + red[(w * 2 + 0) * 512 + tid + 128];
        sc += red[(w * 2 + 1) * 512 + tid] + red[(w * 2 + 1) * 512 + tid + 128];
      }
    }
#pragma unroll
    for (int w = 0; w < 8; ++w) { nq += s_cnt[w]; nc += s_cnt[8 + w]; }
    pooled[b * DIM + tid] = sq / fmaxf(nq, 1e-9f);
    pooled[(NB + b) * DIM + tid] = sc / fmaxf(nc, 1e-9f);
  }
  if (tid == 0) {
    float tot = 0.f;
#pragma unroll
    for (int w = 0; w < 8; ++w) tot += s_wsum[w];
    late[b] = tot;
  }
}

// ================= tail kernels: round-1/9 proven shapes =====================
__global__ __launch_bounds__(DIM)
void mlp_v1(const float* __restrict__ pooled,
            const float* __restrict__ W1, const float* __restrict__ b1,
            const float* __restrict__ W2, const float* __restrict__ b2,
            float* __restrict__ emb) {
  __shared__ float s_in[DIM];
  __shared__ float s_h[DIM];
  __shared__ float s_red[6];
  const int row = blockIdx.y * NB + blockIdx.x;
  const int d = threadIdx.x;
  s_in[d] = pooled[(size_t)row * DIM + d];
  __syncthreads();
  float acc = b1[d];
#pragma unroll 8
  for (int k = 0; k < DIM; ++k) acc = fmaf(s_in[k], W1[k * DIM + d], acc);
  s_h[d] = fmaxf(acc, 0.f);
  __syncthreads();
  float p = b2[d];
#pragma unroll 8
  for (int k = 0; k < DIM; ++k) p = fmaf(s_h[k], W2[k * DIM + d], p);
  float ss = p * p;
#pragma unroll
  for (int o = 32; o; o >>= 1) ss += __shfl_xor(ss, o);
  if ((d & 63) == 0) s_red[d >> 6] = ss;
  __syncthreads();
  float tot = 0.f;
#pragma unroll
  for (int w = 0; w < 6; ++w) tot += s_red[w];
  emb[(size_t)row * DIM + d] = p * (1.0f / fmaxf(sqrtf(tot), 1e-12f));
}

__global__ __launch_bounds__(NB)
void contrast_kernel(const float* __restrict__ emb, float* __restrict__ out0) {
  __shared__ float s_q[DIM];
  const int i = blockIdx.x;
  for (int k = threadIdx.x; k < DIM; k += NB) s_q[k] = emb[(size_t)i * DIM + k];
  __syncthreads();
  const float* ce = emb + (size_t)(NB + threadIdx.x) * DIM;
  float acc = 0.f;
#pragma unroll 8
  for (int k = 0; k < DIM; ++k) acc = fmaf(s_q[k], ce[k], acc);
  out0[(size_t)i * NB + threadIdx.x] = acc / 0.07f;
}

// ============================== launch =======================================
extern "C" void kernel_launch(void* const* d_in, const int* in_sizes, int n_in,
                              void* d_out, int out_size, void* d_ws, size_t ws_size,
                              hipStream_t stream) {
  const float* qtok = (const float*)d_in[0];
  const float* ctok = (const float*)d_in[1];
  const int*   qmm  = (const int*)d_in[2];
  const int*   cmm  = (const int*)d_in[3];
  const float* W1   = (const float*)d_in[4];
  const float* b1   = (const float*)d_in[5];
  const float* W2   = (const float*)d_in[6];
  const float* b2   = (const float*)d_in[7];

  float* out0 = (float*)d_out;            // [NB*NB]
  float* late = out0 + NB * NB;           // [NB]
  float* pooled = (float*)d_ws;           // [2*NB][DIM]
  float* emb    = pooled + 2 * NB * DIM;  // [2*NB][DIM]

  hipLaunchKernelGGL(fused6, dim3(NB), dim3(512), 0, stream,
                     qtok, ctok, qmm, cmm, pooled, late);
  hipLaunchKernelGGL(mlp_v1, dim3(NB, 2), dim3(DIM), 0, stream,
                     pooled, W1, b1, W2, b2, emb);
  hipLaunchKernelGGL(contrast_kernel, dim3(NB), dim3(NB), 0, stream, emb, out0);
}

// Round 15
// 108.139 us; speedup vs baseline: 1.3578x; 1.0463x over previous
//
#include <hip/hip_runtime.h>
#include <hip/hip_bf16.h>
#include <stdint.h>

#define NB 256
#define LQ 128
#define LC 512
#define DIM 384
#define CBP 392     // bf16 tile pitch in shorts (784 B)
#define NST 20      // 4 q tiles + 16 c tiles, 32 rows each

typedef __attribute__((ext_vector_type(8))) short short8;
typedef __attribute__((ext_vector_type(4))) float f4;
typedef __attribute__((ext_vector_type(2))) unsigned int u32x2;

__device__ __forceinline__ unsigned int pk2bf(float a, float b) {
  union { float f; uint32_t u; } x, y; x.f = a; y.f = b;
  uint32_t lo = (x.u + 0x7fffu + ((x.u >> 16) & 1u)) >> 16;
  uint32_t hi = (y.u + 0x7fffu + ((y.u >> 16) & 1u)) >> 16;
  return lo | (hi << 16);
}

// ============== fused single-pass with per-block tile rotation ===============
// Round-15: byte-identical to round-9 fused2 (best: 97 us) EXCEPT each block
// rotates its tile order: q tiles start at (b&3), c tiles at (b&15). All
// blocks were barrier-locked to the SAME intra-batch offset (batch stride
// 192 KB = multiple of any channel interleave period) -> instantaneous
// channel hotspotting. Rotation spreads concurrent reads over 16 distinct
// 48-KB windows. max/sum folds are order-independent; capture conditions and
// mask/qi/ci indices follow the rotation.
__global__ __launch_bounds__(512, 2)
void fused2r(const float* __restrict__ qtok, const float* __restrict__ ctok,
             const int* __restrict__ qm, const int* __restrict__ cm,
             float* __restrict__ pooled, float* __restrict__ late) {
  __shared__ unsigned short s_cb[2][32][CBP];  // 50176 B (epilogue: f32 arena)
  __shared__ float s_qi[LQ];
  __shared__ float s_ci[2][32];
  __shared__ int s_qm[LQ];
  __shared__ int s_cm[LC];
  __shared__ float s_cnt[16];
  __shared__ float s_wsum[8];

  const int b = blockIdx.x, tid = threadIdx.x;
  const int wave = tid >> 6, lane = tid & 63;
  const int rA = lane & 15, hi = lane >> 4;
  const bool hiHalf = lane >= 32;
  const int l31 = lane & 31;
  const int rq = b & 3, rc = b & 15;   // per-block rotations

  const float* qb = qtok + (size_t)b * LQ * DIM;
  const float* cb = ctok + (size_t)b * LC * DIM;

  s_cm[tid] = cm[b * LC + tid];
  if (tid < LQ) s_qm[tid] = qm[b * LQ + tid];
  __syncthreads();

  f4 v0[4], h0[2], v1[4], h1[2];
  f4 pqA = {0,0,0,0}, pqB = {0,0,0,0}, pcA = {0,0,0,0}, pcB = {0,0,0,0};
  float cq = 0.f, cc = 0.f;
  float rm[4] = {-1e9f, -1e9f, -1e9f, -1e9f};
  short8 A[12] = {};

#define TBASE(t) (((t) < 4) ? (qb + (size_t)((((t) + rq) & 3)) * 32 * DIM) \
                            : (cb + (size_t)((((t) - 4 + rc) & 15)) * 32 * DIM))

#define ISSUE(V, H, base_) do {                                              \
    const float* bb_ = (base_);                                              \
    _Pragma("unroll")                                                        \
    for (int i_ = 0; i_ < 4; ++i_)                                           \
      V[i_] = *((const f4*)(bb_ + (size_t)(wave * 4 + i_) * DIM) + lane);    \
    _Pragma("unroll")                                                        \
    for (int j_ = 0; j_ < 2; ++j_)                                           \
      H[j_] = *((const f4*)(bb_ + (size_t)(wave * 4 + 2 * j_ +               \
                (hiHalf ? 1 : 0)) * DIM) + 64 + l31);                        \
  } while (0)

#define STAGE(T, V, H, BUF) do {                                             \
    const int t_ = (T);                                                      \
    if (t_ == NST - 1) { asm volatile("s_waitcnt vmcnt(0)" ::: "memory"); }  \
    else               { asm volatile("s_waitcnt vmcnt(6)" ::: "memory"); }  \
    __builtin_amdgcn_sched_barrier(0);                                       \
    const bool isq_ = t_ < 4;                                                \
    const int rt_ = isq_ ? ((t_ + rq) & 3) : ((t_ - 4 + rc) & 15);           \
    const int* mk_ = isq_ ? (s_qm + rt_ * 32) : (s_cm + rt_ * 32);           \
    float ss_[4];                                                            \
    _Pragma("unroll")                                                        \
    for (int i_ = 0; i_ < 4; ++i_) {                                         \
      const int lr_ = wave * 4 + i_;                                         \
      u32x2 w_; w_[0] = pk2bf(V[i_].x, V[i_].y); w_[1] = pk2bf(V[i_].z, V[i_].w); \
      *(u32x2*)&s_cb[BUF][lr_][4 * lane] = w_;                               \
      ss_[i_] = V[i_].x * V[i_].x + V[i_].y * V[i_].y                        \
              + V[i_].z * V[i_].z + V[i_].w * V[i_].w;                       \
    }                                                                        \
    _Pragma("unroll")                                                        \
    for (int j_ = 0; j_ < 2; ++j_) {                                         \
      const int lr_ = wave * 4 + 2 * j_ + (hiHalf ? 1 : 0);                  \
      u32x2 w_; w_[0] = pk2bf(H[j_].x, H[j_].y); w_[1] = pk2bf(H[j_].z, H[j_].w); \
      *(u32x2*)&s_cb[BUF][lr_][256 + 4 * l31] = w_;                          \
      const float td_ = H[j_].x * H[j_].x + H[j_].y * H[j_].y               \
                      + H[j_].z * H[j_].z + H[j_].w * H[j_].w;              \
      if (hiHalf) ss_[2 * j_ + 1] += td_; else ss_[2 * j_] += td_;           \
    }                                                                        \
    _Pragma("unroll")                                                        \
    for (int o_ = 32; o_; o_ >>= 1) {                                        \
      _Pragma("unroll")                                                      \
      for (int i_ = 0; i_ < 4; ++i_) ss_[i_] += __shfl_xor(ss_[i_], o_);     \
    }                                                                        \
    float fm_[4];                                                            \
    _Pragma("unroll")                                                        \
    for (int i_ = 0; i_ < 4; ++i_) fm_[i_] = (float)mk_[wave * 4 + i_];      \
    if (isq_) {                                                              \
      _Pragma("unroll")                                                      \
      for (int i_ = 0; i_ < 4; ++i_) { pqA += V[i_] * fm_[i_]; cq += fm_[i_]; } \
      _Pragma("unroll")                                                      \
      for (int j_ = 0; j_ < 2; ++j_)                                         \
        pqB += H[j_] * (hiHalf ? fm_[2 * j_ + 1] : fm_[2 * j_]);             \
      if (lane == 0) {                                                       \
        _Pragma("unroll")                                                    \
        for (int i_ = 0; i_ < 4; ++i_)                                       \
          s_qi[rt_ * 32 + wave * 4 + i_] = 1.0f / fmaxf(sqrtf(ss_[i_]), 1e-12f); \
      }                                                                      \
    } else {                                                                 \
      _Pragma("unroll")                                                      \
      for (int i_ = 0; i_ < 4; ++i_) { pcA += V[i_] * fm_[i_]; cc += fm_[i_]; } \
      _Pragma("unroll")                                                      \
      for (int j_ = 0; j_ < 2; ++j_)                                         \
        pcB += H[j_] * (hiHalf ? fm_[2 * j_ + 1] : fm_[2 * j_]);             \
      if (lane == 0) {                                                       \
        _Pragma("unroll")                                                    \
        for (int i_ = 0; i_ < 4; ++i_)                                       \
          s_ci[BUF][wave * 4 + i_] = 1.0f / fmaxf(sqrtf(ss_[i_]), 1e-12f);   \
      }                                                                      \
    }                                                                        \
    if (t_ + 2 < NST) { ISSUE(V, H, TBASE(t_ + 2)); }                        \
    asm volatile("s_waitcnt lgkmcnt(0)" ::: "memory");                       \
    __builtin_amdgcn_s_barrier();                                            \
    __builtin_amdgcn_sched_barrier(0);                                       \
    if (isq_) {                                                              \
      if ((wave >> 1) == rt_) {  /* wave pair owns q rows [32*rt, +32) */    \
        const int lb_ = (wave & 1) * 16 + rA;                                \
        _Pragma("unroll")                                                    \
        for (int kk_ = 0; kk_ < 12; ++kk_)                                   \
          A[kk_] = *(const short8*)&s_cb[BUF][lb_][kk_ * 32 + hi * 8];       \
        asm volatile("s_waitcnt lgkmcnt(0)" ::: "memory");                   \
        __builtin_amdgcn_sched_barrier(0);                                   \
      }                                                                      \
    } else {                                                                 \
      f4 a0_ = {0,0,0,0}, a1_ = {0,0,0,0};                                   \
      _Pragma("unroll")                                                      \
      for (int kk_ = 0; kk_ < 12; ++kk_) {                                   \
        const short8 b0_ = *(const short8*)&s_cb[BUF][rA][kk_ * 32 + hi * 8];     \
        const short8 b1_ = *(const short8*)&s_cb[BUF][rA + 16][kk_ * 32 + hi * 8];\
        a0_ = __builtin_amdgcn_mfma_f32_16x16x32_bf16(A[kk_], b0_, a0_, 0, 0, 0); \
        a1_ = __builtin_amdgcn_mfma_f32_16x16x32_bf16(A[kk_], b1_, a1_, 0, 0, 0); \
      }                                                                      \
      const int tb_ = rt_ * 32;                                              \
      const bool m0_ = s_cm[tb_ + rA] != 0;                                  \
      const bool m1_ = s_cm[tb_ + rA + 16] != 0;                             \
      const float ci0_ = s_ci[BUF][rA], ci1_ = s_ci[BUF][rA + 16];           \
      _Pragma("unroll")                                                      \
      for (int r_ = 0; r_ < 4; ++r_) {                                       \
        const float qi_ = s_qi[wave * 16 + hi * 4 + r_];                     \
        const float x0_ = m0_ ? a0_[r_] * (qi_ * ci0_) : -1e9f;              \
        const float x1_ = m1_ ? a1_[r_] * (qi_ * ci1_) : -1e9f;              \
        rm[r_] = fmaxf(rm[r_], fmaxf(x0_, x1_));                             \
      }                                                                      \
    }                                                                        \
  } while (0)

  // prologue: banks for tiles 0 and 1 in flight
  ISSUE(v0, h0, TBASE(0));
  ISSUE(v1, h1, TBASE(1));

  for (int t = 0; t < NST; t += 2) {
    STAGE(t, v0, h0, 0);
    STAGE(t + 1, v1, h1, 1);
  }

  // ---------------- epilogue ----------------
#pragma unroll
  for (int r = 0; r < 4; ++r) {
#pragma unroll
    for (int o = 1; o < 16; o <<= 1) rm[r] = fmaxf(rm[r], __shfl_xor(rm[r], o));
  }
  float ps = 0.f;
  if (rA == 0) {
    const int rowb = wave * 16 + hi * 4;
#pragma unroll
    for (int r = 0; r < 4; ++r) ps += s_qm[rowb + r] ? rm[r] : 0.f;
  }
#pragma unroll
  for (int o = 32; o; o >>= 1) ps += __shfl_xor(ps, o);
  if (lane == 0) s_wsum[wave] = ps;

  __syncthreads();  // stage-19 LDS reads done before arena reuse

  float* red = (float*)&s_cb[0][0][0];  // [8 waves][2 (q,c)][512] f32 = 32 KB
  *(f4*)&red[(wave * 2 + 0) * 512 + 4 * lane] = pqA;
  *(f4*)&red[(wave * 2 + 0) * 512 + 256 + (hiHalf ? 128 : 0) + 4 * l31] = pqB;
  *(f4*)&red[(wave * 2 + 1) * 512 + 4 * lane] = pcA;
  *(f4*)&red[(wave * 2 + 1) * 512 + 256 + (hiHalf ? 128 : 0) + 4 * l31] = pcB;
  if (lane == 0) { s_cnt[wave] = cq; s_cnt[8 + wave] = cc; }
  __syncthreads();

  if (tid < DIM) {
    float sq = 0.f, sc = 0.f, nq = 0.f, nc = 0.f;
    if (tid < 256) {
#pragma unroll
      for (int w = 0; w < 8; ++w) {
        sq += red[(w * 2 + 0) * 512 + tid];
        sc += red[(w * 2 + 1) * 512 + tid];
      }
    } else {
#pragma unroll
      for (int w = 0; w < 8; ++w) {
        sq += red[(w * 2 + 0) * 512 + tid] + red[(w * 2 + 0) * 512 + tid + 128];
        sc += red[(w * 2 + 1) * 512 + tid] + red[(w * 2 + 1) * 512 + tid + 128];
      }
    }
#pragma unroll
    for (int w = 0; w < 8; ++w) { nq += s_cnt[w]; nc += s_cnt[8 + w]; }
    pooled[b * DIM + tid] = sq / fmaxf(nq, 1e-9f);
    pooled[(NB + b) * DIM + tid] = sc / fmaxf(nc, 1e-9f);
  }
  if (tid == 0) {
    float tot = 0.f;
#pragma unroll
    for (int w = 0; w < 8; ++w) tot += s_wsum[w];
    late[b] = tot;
  }
}

// ================= tail kernels: round-1/9 proven shapes =====================
__global__ __launch_bounds__(DIM)
void mlp_v1(const float* __restrict__ pooled,
            const float* __restrict__ W1, const float* __restrict__ b1,
            const float* __restrict__ W2, const float* __restrict__ b2,
            float* __restrict__ emb) {
  __shared__ float s_in[DIM];
  __shared__ float s_h[DIM];
  __shared__ float s_red[6];
  const int row = blockIdx.y * NB + blockIdx.x;
  const int d = threadIdx.x;
  s_in[d] = pooled[(size_t)row * DIM + d];
  __syncthreads();
  float acc = b1[d];
#pragma unroll 8
  for (int k = 0; k < DIM; ++k) acc = fmaf(s_in[k], W1[k * DIM + d], acc);
  s_h[d] = fmaxf(acc, 0.f);
  __syncthreads();
  float p = b2[d];
#pragma unroll 8
  for (int k = 0; k < DIM; ++k) p = fmaf(s_h[k], W2[k * DIM + d], p);
  float ss = p * p;
#pragma unroll
  for (int o = 32; o; o >>= 1) ss += __shfl_xor(ss, o);
  if ((d & 63) == 0) s_red[d >> 6] = ss;
  __syncthreads();
  float tot = 0.f;
#pragma unroll
  for (int w = 0; w < 6; ++w) tot += s_red[w];
  emb[(size_t)row * DIM + d] = p * (1.0f / fmaxf(sqrtf(tot), 1e-12f));
}

__global__ __launch_bounds__(NB)
void contrast_kernel(const float* __restrict__ emb, float* __restrict__ out0) {
  __shared__ float s_q[DIM];
  const int i = blockIdx.x;
  for (int k = threadIdx.x; k < DIM; k += NB) s_q[k] = emb[(size_t)i * DIM + k];
  __syncthreads();
  const float* ce = emb + (size_t)(NB + threadIdx.x) * DIM;
  float acc = 0.f;
#pragma unroll 8
  for (int k = 0; k < DIM; ++k) acc = fmaf(s_q[k], ce[k], acc);
  out0[(size_t)i * NB + threadIdx.x] = acc / 0.07f;
}

// ============================== launch =======================================
extern "C" void kernel_launch(void* const* d_in, const int* in_sizes, int n_in,
                              void* d_out, int out_size, void* d_ws, size_t ws_size,
                              hipStream_t stream) {
  const float* qtok = (const float*)d_in[0];
  const float* ctok = (const float*)d_in[1];
  const int*   qmm  = (const int*)d_in[2];
  const int*   cmm  = (const int*)d_in[3];
  const float* W1   = (const float*)d_in[4];
  const float* b1   = (const float*)d_in[5];
  const float* W2   = (const float*)d_in[6];
  const float* b2   = (const float*)d_in[7];

  float* out0 = (float*)d_out;            // [NB*NB]
  float* late = out0 + NB * NB;           // [NB]
  float* pooled = (float*)d_ws;           // [2*NB][DIM]
  float* emb    = pooled + 2 * NB * DIM;  // [2*NB][DIM]

  hipLaunchKernelGGL(fused2r, dim3(NB), dim3(512), 0, stream,
                     qtok, ctok, qmm, cmm, pooled, late);
  hipLaunchKernelGGL(mlp_v1, dim3(NB, 2), dim3(DIM), 0, stream,
                     pooled, W1, b1, W2, b2, emb);
  hipLaunchKernelGGL(contrast_kernel, dim3(NB), dim3(NB), 0, stream, emb, out0);
}